// Round 7
// baseline (51.808 us; speedup 1.0000x reference)
//
#include <hip/hip_runtime.h>
#include <hip/hip_bf16.h>

typedef __attribute__((ext_vector_type(8))) __bf16 bf16x8;
typedef __attribute__((ext_vector_type(4))) float f32x4;

#define SEQ    4096
#define HDIM   64
#define BKT    64
#define STRIP  4          // buckets per block
#define KSLOTB 8192       // bytes per LDS slot (64 rows x 64 cols x 2B)

__device__ __forceinline__ unsigned f2bf_u(float f) {
    unsigned u = __float_as_uint(f);
    u += 0x7FFFu + ((u >> 16) & 1u);
    return u >> 16;
}
__device__ __forceinline__ unsigned pk2(float a, float b) {
    return f2bf_u(a) | (f2bf_u(b) << 16);
}
__device__ __forceinline__ int swzV(int row) {
    return ((row & 7) ^ ((row >> 3) & 7)) << 4;
}

__global__ void __launch_bounds__(256, 3) local_attn_kernel(
    const float* __restrict__ q, const float* __restrict__ k,
    const float* __restrict__ v, float* __restrict__ out)
{
    // 2-slot rings: slot (bucket&1) holds that bucket's K / V^T (bf16, swizzled)
    __shared__ __align__(16) unsigned short sK[2 * 64 * 64];
    __shared__ __align__(16) unsigned short sVt[2 * 64 * 64];

    const int tid = threadIdx.x;
    const int bid = blockIdx.x;
    // XCD-aware bijective swizzle (1024 = 8 * 128): same-XCD neighbors are
    // consecutive strips of the same bh row -> boundary-bucket K/V L2 hits.
    const int lg = (bid & 7) * 128 + (bid >> 3);
    const int bh = lg >> 4;
    const int strip = lg & 15;
    const int b0 = strip * STRIP;

    const int base = bh * SEQ * HDIM;

    const int lane = tid & 63;
    const int wid  = tid >> 6;
    const int g = lane >> 4, m = lane & 15;
    const int g4 = g * 4;
    const int qbase = wid * 16;
    const int qb = qbase + m;            // query row within bucket (constant)

    char* const sKb = reinterpret_cast<char*>(sK);
    char* const sVb = reinterpret_cast<char*>(sVt);

    const float scale = 0.125f * 1.44269504f;   // 64^-0.5 * log2(e)
    bf16x8 bq[2];                        // loop-carried Q fragments (current bucket)

    // ================= prologue: stage buckets b0-1 (slot1) and b0 (slot0) ==========
    {
        const int win0 = base + (b0 - 1) * BKT * HDIM;
        float4 kreg[8], vreg[8], qreg[4];
        #pragma unroll
        for (int i = 0; i < 8; ++i) {
            kreg[i] = make_float4(0.f, 0.f, 0.f, 0.f);
            if (strip > 0 || i >= 4)
                kreg[i] = *reinterpret_cast<const float4*>(k + win0 + i * 1024 + tid * 4);
        }
        #pragma unroll
        for (int i = 0; i < 8; ++i) {
            const int kb = i * 16 + wid * 4;
            vreg[i] = make_float4(0.f, 0.f, 0.f, 0.f);
            if (strip > 0 || i >= 4)
                vreg[i] = *reinterpret_cast<const float4*>(v + win0 + (kb + g) * HDIM + m * 4);
        }
        const int qoff0 = base + b0 * BKT * HDIM;
        #pragma unroll
        for (int h = 0; h < 2; ++h) {
            const float* qp = q + qoff0 + qb * HDIM + h * 32 + g * 8;
            qreg[2 * h]     = *reinterpret_cast<const float4*>(qp);
            qreg[2 * h + 1] = *reinterpret_cast<const float4*>(qp + 4);
        }
        __builtin_amdgcn_sched_barrier(0);
        #pragma unroll
        for (int i = 0; i < 8; ++i) {
            const int flat = i * 1024 + tid * 4;
            const int lr = (flat >> 6) & 63, col = flat & 63;
            uint2 p;
            p.x = pk2(kreg[i].x, kreg[i].y);
            p.y = pk2(kreg[i].z, kreg[i].w);
            const int byte = ((i < 4) ? KSLOTB : 0) + ((lr * 128 + col * 2) ^ ((lr & 7) << 4));
            *reinterpret_cast<uint2*>(sKb + byte) = p;
        }
        #pragma unroll
        for (int i = 0; i < 8; ++i) {
            const int kbl = (i * 16 + wid * 4) & 63;
            const float4 f = vreg[i];
            const unsigned P0 = pk2(f.x, f.y);
            const unsigned P1 = pk2(f.z, f.w);
            const unsigned own  = (g < 2) ? P0 : P1;
            const unsigned send = (g < 2) ? P1 : P0;
            const unsigned R = __shfl_xor(send, 32);
            const unsigned T = __shfl_xor(own, 16);
            const unsigned U = __shfl_xor(R, 16);
            const unsigned A0 = (g < 2) ? own : R;
            const unsigned A1 = (g < 2) ? T : U;
            const unsigned A2 = (g < 2) ? R : own;
            const unsigned A3 = (g < 2) ? U : T;
            const int sdx = g & 1;
            const unsigned k0 = sdx ? A1 : A0, k1 = sdx ? A0 : A1;
            const unsigned k2 = sdx ? A3 : A2, k3 = sdx ? A2 : A3;
            const unsigned G0 = sdx ? ((k0 >> 16) | (k1 & 0xFFFF0000u)) : ((k0 & 0xFFFFu) | (k1 << 16));
            const unsigned G1 = sdx ? ((k2 >> 16) | (k3 & 0xFFFF0000u)) : ((k2 & 0xFFFFu) | (k3 << 16));
            const int er = m * 4 + g;
            const int byte = ((i < 4) ? KSLOTB : 0) + ((er * 128 + kbl * 2) ^ swzV(er));
            uint2 p; p.x = G0; p.y = G1;
            *reinterpret_cast<uint2*>(sVb + byte) = p;
        }
        #pragma unroll
        for (int h = 0; h < 2; ++h) {
            uint4 u;
            u.x = pk2(qreg[2 * h].x * scale, qreg[2 * h].y * scale);
            u.y = pk2(qreg[2 * h].z * scale, qreg[2 * h].w * scale);
            u.z = pk2(qreg[2 * h + 1].x * scale, qreg[2 * h + 1].y * scale);
            u.w = pk2(qreg[2 * h + 1].z * scale, qreg[2 * h + 1].w * scale);
            bq[h] = __builtin_bit_cast(bf16x8, u);
        }
        __syncthreads();
    }

    // ================= main loop over the strip's buckets ===========================
    #pragma unroll
    for (int jj = 0; jj < STRIP; ++jj) {
        const int qoffj = base + (b0 + jj) * BKT * HDIM;
        const int scur = (jj & 1) * KSLOTB;   // current bucket's slot
        const int spre = scur ^ KSLOTB;       // previous bucket's slot

        // ---- issue next bucket's loads (consumed after the barrier below) ----
        float4 kn[4], vn[4], qn[4];
        if (jj < STRIP - 1) {
            const int noff = qoffj + BKT * HDIM;
            #pragma unroll
            for (int i = 0; i < 4; ++i)
                kn[i] = *reinterpret_cast<const float4*>(k + noff + i * 1024 + tid * 4);
            #pragma unroll
            for (int i = 0; i < 4; ++i) {
                const int kbl = i * 16 + wid * 4;
                vn[i] = *reinterpret_cast<const float4*>(v + noff + (kbl + g) * HDIM + m * 4);
            }
            #pragma unroll
            for (int h = 0; h < 2; ++h) {
                const float* qp = q + noff + qb * HDIM + h * 32 + g * 8;
                qn[2 * h]     = *reinterpret_cast<const float4*>(qp);
                qn[2 * h + 1] = *reinterpret_cast<const float4*>(qp + 4);
            }
            __builtin_amdgcn_sched_barrier(0);
        }

        // ---- S^T = K * Q^T : lane holds S^T[c*16+g*4+r][qb] ----
        f32x4 acc[8];
        #pragma unroll
        for (int c = 0; c < 8; ++c) acc[c] = (f32x4){0.f, 0.f, 0.f, 0.f};
        __builtin_amdgcn_s_setprio(1);
        #pragma unroll
        for (int c = 0; c < 8; ++c) {
            const int lr = (c & 3) * 16 + m;
            const int sb = (c < 4) ? spre : scur;
            #pragma unroll
            for (int h = 0; h < 2; ++h) {
                const int byte = sb + ((lr * 128 + h * 64 + g * 16) ^ ((m & 7) << 4));
                const bf16x8 ak = *reinterpret_cast<const bf16x8*>(sKb + byte);
                acc[c] = __builtin_amdgcn_mfma_f32_16x16x32_bf16(ak, bq[h], acc[c], 0, 0, 0);
            }
        }
        __builtin_amdgcn_s_setprio(0);

        // ---- mask + exact softmax (exp2 domain) ----
        const bool dead_prev = (strip == 0 && jj == 0);
        float mx = -3e38f;
        #pragma unroll
        for (int c = 0; c < 8; ++c) {
            #pragma unroll
            for (int r = 0; r < 4; ++r) {
                const int kk = c * 16 + g4 + r;
                const bool dead = (c >= 4) ? (kk - 64 > qb) : dead_prev;
                const float s = dead ? -1e30f : acc[c][r];
                acc[c][r] = s;
                mx = fmaxf(mx, s);
            }
        }
        mx = fmaxf(mx, __shfl_xor(mx, 16));
        mx = fmaxf(mx, __shfl_xor(mx, 32));
        float sum = 0.f;
        uint2 pb[8];
        #pragma unroll
        for (int c = 0; c < 8; ++c) {
            const float p0 = __builtin_amdgcn_exp2f(acc[c][0] - mx);
            const float p1 = __builtin_amdgcn_exp2f(acc[c][1] - mx);
            const float p2 = __builtin_amdgcn_exp2f(acc[c][2] - mx);
            const float p3 = __builtin_amdgcn_exp2f(acc[c][3] - mx);
            sum += (p0 + p1) + (p2 + p3);
            pb[c].x = pk2(p0, p1);
            pb[c].y = pk2(p2, p3);
        }
        sum += __shfl_xor(sum, 16);
        sum += __shfl_xor(sum, 32);
        const float rl = 1.0f / sum;

        // ---- P redistribution via shuffles ----
        const int l0 = m + ((g & 1) << 5);
        const int l1 = l0 + 16;
        const bool hi = (g >> 1) != 0;
        bf16x8 bp[4];
        #pragma unroll
        for (int kt = 0; kt < 4; ++kt) {
            const unsigned a0x = __shfl(pb[2 * kt].x, l0),     a0y = __shfl(pb[2 * kt].y, l0);
            const unsigned a1x = __shfl(pb[2 * kt + 1].x, l0), a1y = __shfl(pb[2 * kt + 1].y, l0);
            const unsigned b0x = __shfl(pb[2 * kt].x, l1),     b0y = __shfl(pb[2 * kt].y, l1);
            const unsigned b1x = __shfl(pb[2 * kt + 1].x, l1), b1y = __shfl(pb[2 * kt + 1].y, l1);
            uint4 u;
            u.x = hi ? a1x : a0x;
            u.y = hi ? a1y : a0y;
            u.z = hi ? b1x : b0x;
            u.w = hi ? b1y : b0y;
            bp[kt] = __builtin_bit_cast(bf16x8, u);
        }

        // ---- O^T = V^T * P^T ----
        f32x4 oacc[4];
        #pragma unroll
        for (int et = 0; et < 4; ++et) oacc[et] = (f32x4){0.f, 0.f, 0.f, 0.f};
        __builtin_amdgcn_s_setprio(1);
        #pragma unroll
        for (int et = 0; et < 4; ++et) {
            const int row = et * 16 + m;
            #pragma unroll
            for (int kt = 0; kt < 4; ++kt) {
                const int sb = (kt < 2) ? spre : scur;
                const int kcol = (kt & 1) * 32 + g * 8;
                const int byte = sb + ((row * 128 + kcol * 2) ^ swzV(row));
                const bf16x8 av = *reinterpret_cast<const bf16x8*>(sVb + byte);
                oacc[et] = __builtin_amdgcn_mfma_f32_16x16x32_bf16(av, bp[kt], oacc[et], 0, 0, 0);
            }
        }
        __builtin_amdgcn_s_setprio(0);

        // ---- store bucket j's output ----
        #pragma unroll
        for (int et = 0; et < 4; ++et) {
            f32x4 o = oacc[et];
            o[0] *= rl; o[1] *= rl; o[2] *= rl; o[3] *= rl;
            *reinterpret_cast<float4*>(out + qoffj + qb * HDIM + et * 16 + g4) =
                *reinterpret_cast<float4*>(&o);
        }

        // ---- stage bucket j+1 into slot spre (prev bucket no longer needed) ----
        if (jj < STRIP - 1) {
            __syncthreads();   // everyone done reading slot spre
            #pragma unroll
            for (int i = 0; i < 4; ++i) {
                const int flat = i * 1024 + tid * 4;
                const int lr = flat >> 6, col = flat & 63;
                uint2 p;
                p.x = pk2(kn[i].x, kn[i].y);
                p.y = pk2(kn[i].z, kn[i].w);
                const int byte = spre + ((lr * 128 + col * 2) ^ ((lr & 7) << 4));
                *reinterpret_cast<uint2*>(sKb + byte) = p;
            }
            #pragma unroll
            for (int i = 0; i < 4; ++i) {
                const int kbl = i * 16 + wid * 4;
                const float4 f = vn[i];
                const unsigned P0 = pk2(f.x, f.y);
                const unsigned P1 = pk2(f.z, f.w);
                const unsigned own  = (g < 2) ? P0 : P1;
                const unsigned send = (g < 2) ? P1 : P0;
                const unsigned R = __shfl_xor(send, 32);
                const unsigned T = __shfl_xor(own, 16);
                const unsigned U = __shfl_xor(R, 16);
                const unsigned A0 = (g < 2) ? own : R;
                const unsigned A1 = (g < 2) ? T : U;
                const unsigned A2 = (g < 2) ? R : own;
                const unsigned A3 = (g < 2) ? U : T;
                const int sdx = g & 1;
                const unsigned k0 = sdx ? A1 : A0, k1 = sdx ? A0 : A1;
                const unsigned k2 = sdx ? A3 : A2, k3 = sdx ? A2 : A3;
                const unsigned G0 = sdx ? ((k0 >> 16) | (k1 & 0xFFFF0000u)) : ((k0 & 0xFFFFu) | (k1 << 16));
                const unsigned G1 = sdx ? ((k2 >> 16) | (k3 & 0xFFFF0000u)) : ((k2 & 0xFFFFu) | (k3 << 16));
                const int er = m * 4 + g;
                const int byte = spre + ((er * 128 + kbl * 2) ^ swzV(er));
                uint2 p; p.x = G0; p.y = G1;
                *reinterpret_cast<uint2*>(sVb + byte) = p;
            }
            #pragma unroll
            for (int h = 0; h < 2; ++h) {
                uint4 u;
                u.x = pk2(qn[2 * h].x * scale, qn[2 * h].y * scale);
                u.y = pk2(qn[2 * h].z * scale, qn[2 * h].w * scale);
                u.z = pk2(qn[2 * h + 1].x * scale, qn[2 * h + 1].y * scale);
                u.w = pk2(qn[2 * h + 1].z * scale, qn[2 * h + 1].w * scale);
                bq[h] = __builtin_bit_cast(bf16x8, u);
            }
            __syncthreads();   // writes visible before next bucket's compute
        }
    }
}

extern "C" void kernel_launch(void* const* d_in, const int* in_sizes, int n_in,
                              void* d_out, int out_size, void* d_ws, size_t ws_size,
                              hipStream_t stream) {
    const float* q = (const float*)d_in[0];
    const float* k = (const float*)d_in[1];
    const float* v = (const float*)d_in[2];
    float* out = (float*)d_out;
    const int bh = in_sizes[0] / (SEQ * HDIM);               // 64
    const int nblocks = bh * (SEQ / BKT / STRIP);            // 64 * 16 = 1024
    hipLaunchKernelGGL(local_attn_kernel, dim3(nblocks), dim3(256), 0, stream,
                       q, k, v, out);
}